// Round 10
// baseline (93.841 us; speedup 1.0000x reference)
//
#include <hip/hip_runtime.h>

#define N_ 4096
#define K_ 64
#define E_ (N_*K_)
#define H_ 256
#define EPS_ 1e-5f
#define L2E_ 1.4426950408889634f   // log2(e)
#define TL2E_ 2.8853900817779268f  // 2*log2(e)

#if __has_builtin(__builtin_amdgcn_exp2f)
#define EXP2(x) __builtin_amdgcn_exp2f(x)
#else
#define EXP2(x) __expf((x) * 0.6931471805599453f)
#endif

// tanh(x) = 1 - 2/(2^(2*log2e*x)+1); inf-safe (exp2(+inf)->inf, rcp(inf)=0)
__device__ __forceinline__ float ftanh(float x) {
    float e = EXP2(x * TL2E_);
    return 1.0f - 2.0f * __builtin_amdgcn_rcpf(e + 1.0f);
}

// One block: W01g[5*256] = TL2E * {W0@W1 (4 rows); b0@W1 + b1};
// swp[0] = sum(W2)+b2; zeroes sums[512] for reduce's atomics.
__global__ __launch_bounds__(256) void prep_kernel(
    const float* __restrict__ W0, const float* __restrict__ b0,
    const float* __restrict__ W1, const float* __restrict__ b1,
    const float* __restrict__ W2, const float* __restrict__ b2,
    float* __restrict__ W01g, float* __restrict__ swp, float* __restrict__ sums)
{
    int c = threadIdx.x;
    float a0 = 0.f, a1 = 0.f, a2 = 0.f, a3 = 0.f, ab = 0.f;
    #pragma unroll 8
    for (int h = 0; h < H_; ++h) {
        float w = W1[h * H_ + c];
        a0 = fmaf(W0[h], w, a0);
        a1 = fmaf(W0[H_ + h], w, a1);
        a2 = fmaf(W0[2 * H_ + h], w, a2);
        a3 = fmaf(W0[3 * H_ + h], w, a3);
        ab = fmaf(b0[h], w, ab);
    }
    W01g[c]          = TL2E_ * a0;
    W01g[H_ + c]     = TL2E_ * a1;
    W01g[2 * H_ + c] = TL2E_ * a2;
    W01g[3 * H_ + c] = TL2E_ * a3;
    W01g[4 * H_ + c] = TL2E_ * (ab + b1[c]);
    sums[c] = 0.f;
    sums[H_ + c] = 0.f;

    __shared__ float red[256];
    red[c] = W2[c];
    __syncthreads();
    for (int s = 128; s > 0; s >>= 1) {
        if (c < s) red[c] += red[c + s];
        __syncthreads();
    }
    if (c == 0) swp[0] = red[0] + b2[0];
}

// Fused att+stats, block = 256 edges (4 rows). Stages tanh quads once.
// Phase A (wave=row): attention, dedup mask, geo/ang gather ->
//   D[e] = leader ? exp(-asum*geo)*ang : 0, P[e] = row<<12|col, M[e] = mask.
// Phase B (thread=column): per-column sums of r, r^2 over the 256 staged
//   quads -> part[block][512]. No atomics.
__global__ __launch_bounds__(256, 4) void attstats_kernel(
    const float* __restrict__ coor, const int* __restrict__ idx,
    const float* __restrict__ geo, const float* __restrict__ ang,
    const float* __restrict__ Wq, const float* __restrict__ bq,
    const float* __restrict__ Wk, const float* __restrict__ bk,
    const float* __restrict__ W01g,
    float* __restrict__ D, unsigned int* __restrict__ P,
    unsigned long long* __restrict__ M, float* __restrict__ part)
{
    __shared__ float4 T4[256];
    const int t = threadIdx.x;
    const int e = blockIdx.x * 256 + t;
    const int lane = t & 63;
    const int row = e >> 6;                 // K_ = 64

    float4 ce = reinterpret_cast<const float4*>(coor)[e];
    T4[t] = make_float4(ftanh(ce.x), ftanh(ce.y), ftanh(ce.z), ftanh(ce.w));
    float ex = ce.x + ce.z, ey = ce.y + ce.w;
    const int col = idx[E_ + e];

    // ---- phase A: attention + dedup (wave = row) ----
    float sx = __shfl(ex, 0), sy = __shfl(ey, 0);   // row center = lane 0
    float att = 0.f;
    #pragma unroll
    for (int j = 0; j < 8; ++j) {
        float qj = fmaf(sy, Wq[8 + j], fmaf(sx, Wq[j], bq[j]));
        float kj = fmaf(ey, Wk[8 + j], fmaf(ex, Wk[j], bk[j]));
        att = fmaf(qj, kj, att);
    }
    att = fabsf(att);

    unsigned long long m = 0;
    float asum = att;
    bool leader = true;
    for (int j = 0; j < 64; ++j) {
        int   bc = __shfl(col, j);
        float ba = __shfl(att, j);
        if (bc == col) {
            m |= (1ull << j);
            if (j < lane) leader = false;
            if (j != lane) asum += ba;
        }
    }
    float d = 0.f;
    if (leader) {
        size_t pp = (size_t)row * N_ + col;
        d = __expf(-asum * geo[pp]) * ang[pp];
    }
    D[e] = d;
    P[e] = ((unsigned)row << 12) | (unsigned)col;
    M[e] = leader ? m : 0ull;

    __syncthreads();   // T4 ready

    // ---- phase B: stats (thread = column) ----
    const float w0 = W01g[t],          w1 = W01g[H_ + t];
    const float w2 = W01g[2 * H_ + t], w3 = W01g[3 * H_ + t];
    const float bb = W01g[4 * H_ + t];
    float sr = 0.f, sr2 = 0.f;
    #pragma unroll 8
    for (int i = 0; i < 256; ++i) {
        float4 q = T4[i];   // broadcast, conflict-free
        float u = fmaf(q.w, w3, fmaf(q.z, w2, fmaf(q.y, w1, fmaf(q.x, w0, bb))));
        float r = __builtin_amdgcn_rcpf(EXP2(u) + 1.0f);
        sr += r;
        sr2 = fmaf(r, r, sr2);
    }
    part[blockIdx.x * 512 + t] = sr;
    part[blockIdx.x * 512 + 256 + t] = sr2;
}

// Row-wise coalesced reduce over 1024 part-rows: 32 blocks x 512 threads,
// 32 rows each, one atomicAdd per thread (32-deep chains).
__global__ __launch_bounds__(512) void reduce_kernel(
    const float* __restrict__ part, float* __restrict__ sums)
{
    int t = threadIdx.x;
    int b0 = blockIdx.x * 32;
    float local = 0.f;
    #pragma unroll 8
    for (int b = b0; b < b0 + 32; ++b) local += part[b * 512 + t];
    atomicAdd(&sums[t], local);
}

// Fold BN+weights into per-column record, exp2-prescaled (R5's finalize).
__global__ __launch_bounds__(256) void finalize_kernel(
    const float* __restrict__ sums, const float* __restrict__ gamma,
    const float* __restrict__ beta, const float* __restrict__ W2,
    const float* __restrict__ W01g, float* __restrict__ folded)
{
    int c = threadIdx.x;
    const float inv = 1.0f / (float)E_;
    float sp = sums[c] * inv;
    float sq = sums[256 + c] * inv;
    float mu = 1.0f - 2.0f * sp;            // mean of h = 1-2r
    float var = 4.0f * fmaf(-sp, sp, sq);
    float a  = gamma[c] * rsqrtf(var + EPS_);
    float bf = fmaf(-mu, a, beta[c]);
    folded[8 * c + 0] = W01g[c];
    folded[8 * c + 1] = W01g[H_ + c];
    folded[8 * c + 2] = W01g[2 * H_ + c];
    folded[8 * c + 3] = W01g[3 * H_ + c];
    folded[8 * c + 4] = W01g[4 * H_ + c];
    folded[8 * c + 5] = -4.0f * L2E_ * a;   // coeff of r
    folded[8 * c + 6] = TL2E_ * (a + bf);   // const term
    folded[8 * c + 7] = -2.0f * W2[c];      // acc coeff on r2
}

// Edge kernel: R5's proven staging (folded-table load, zero-fill pre-barrier)
// + R9's proven light tail (mask-based dup handling, predicated store).
// Block = 2 rows (128 edges), thread = 4 edges x 32 columns.
__global__ __launch_bounds__(256, 8) void edge_kernel(
    const float* __restrict__ coor, const float* __restrict__ folded,
    const float* __restrict__ swp,
    const float* __restrict__ D, const unsigned int* __restrict__ P,
    const unsigned long long* __restrict__ M,
    float* __restrict__ out)
{
    __shared__ float4 FS[2 * H_];   // folded per-column records
    __shared__ float4 TS[128];      // per-edge tanh quads
    __shared__ float  ACC[8][128];  // chunk x edge partial accs

    const int t = threadIdx.x;
    const int row0 = blockIdx.x * 2;
    const int eb0 = blockIdx.x * 128;

    {
        const float4* F = reinterpret_cast<const float4*>(folded);
        FS[t] = F[t];
        FS[t + 256] = F[t + 256];
    }
    float De = 0.f;
    unsigned int Pe = 0;
    unsigned long long Me = 0;
    if (t < 128) {
        float4 ce = reinterpret_cast<const float4*>(coor)[eb0 + t];
        TS[t] = make_float4(ftanh(ce.x), ftanh(ce.y), ftanh(ce.z), ftanh(ce.w));
        De = D[eb0 + t];
        Pe = P[eb0 + t];
        Me = M[eb0 + t];
    }
    {   // zero-fill this block's 2 rows (replaces 64MB memset); R5 position
        float4 z = make_float4(0.f, 0.f, 0.f, 0.f);
        float4* orow = reinterpret_cast<float4*>(out + (size_t)row0 * N_);
        #pragma unroll
        for (int i = 0; i < 8; ++i) orow[i * 256 + t] = z;
    }
    __syncthreads();

    // ---- compute: 4 edges x 32 columns per thread ----
    const int eg = (t & 31) * 4;
    const int chunk = t >> 5;
    const float4 tq0 = TS[eg], tq1 = TS[eg + 1], tq2 = TS[eg + 2], tq3 = TS[eg + 3];
    const float4* Fp = &FS[chunk * 64];
    float a0 = 0.f, a1 = 0.f, a2 = 0.f, a3 = 0.f;
    #pragma unroll 4
    for (int i = 0; i < 32; ++i) {
        float4 f0 = Fp[2 * i];
        float4 f1 = Fp[2 * i + 1];
        #define EVAL(tq, ak) { \
            float u = fmaf(tq.w, f0.w, fmaf(tq.z, f0.z, fmaf(tq.y, f0.y, fmaf(tq.x, f0.x, f1.x)))); \
            float r = __builtin_amdgcn_rcpf(EXP2(u) + 1.0f); \
            float r2 = __builtin_amdgcn_rcpf(EXP2(fmaf(r, f1.y, f1.z)) + 1.0f); \
            ak = fmaf(r2, f1.w, ak); }
        EVAL(tq0, a0) EVAL(tq1, a1) EVAL(tq2, a2) EVAL(tq3, a3)
        #undef EVAL
    }
    *reinterpret_cast<float4*>(&ACC[chunk][eg]) = make_float4(a0, a1, a2, a3);
    __syncthreads();

    // ---- write phase: waves 0,1 (one lane per edge), light tail ----
    const int w = t >> 6, lane = t & 63;
    if (w < 2) {
        float val = swp[0];
        #pragma unroll
        for (int c = 0; c < 8; ++c) val += ACC[c][t];
        val = fmaxf(val, 0.f);

        // sum duplicate lanes' vals (rare); all lanes stay active for shfl
        float vsum = val;
        unsigned long long m2 = Me & ~(1ull << lane);
        while (__any(m2 != 0ull)) {
            unsigned long long pick = m2 ? m2 : 1ull;
            int j = __ffsll((unsigned long long)pick) - 1;
            float bv = __shfl(val, j);
            if (m2) { vsum += bv; m2 &= m2 - 1; }
        }
        if (De != 0.f) out[Pe] = vsum * De;
    }
}

extern "C" void kernel_launch(void* const* d_in, const int* in_sizes, int n_in,
                              void* d_out, int out_size, void* d_ws, size_t ws_size,
                              hipStream_t stream)
{
    const float* coor  = (const float*)d_in[1];
    const int*   idx   = (const int*)d_in[2];
    const float* geo   = (const float*)d_in[3];
    const float* ang   = (const float*)d_in[4];
    const float* W0    = (const float*)d_in[5];
    const float* b0    = (const float*)d_in[6];
    const float* W1    = (const float*)d_in[7];
    const float* b1    = (const float*)d_in[8];
    const float* gamma = (const float*)d_in[9];
    const float* beta  = (const float*)d_in[10];
    const float* W2    = (const float*)d_in[11];
    const float* b2    = (const float*)d_in[12];
    const float* Wq    = (const float*)d_in[13];
    const float* bq    = (const float*)d_in[14];
    const float* Wk    = (const float*)d_in[15];
    const float* bk    = (const float*)d_in[16];

    char* ws = (char*)d_ws;
    float*              swp    = (float*)ws;                   // 1
    float*              sums   = (float*)(ws + 1024);          // 512
    float*              W01g   = (float*)(ws + 4096);          // 1280
    float*              folded = (float*)(ws + 10240);         // 2048
    float*              D      = (float*)(ws + 20480);                            // E f32 (1MB)
    unsigned int*       P      = (unsigned int*)(ws + 20480 + (size_t)E_ * 4);    // E u32 (1MB)
    unsigned long long* M      = (unsigned long long*)(ws + 20480 + (size_t)E_ * 8); // E u64 (2MB)
    float*              part   = (float*)(ws + 20480 + (size_t)E_ * 16);          // 1024*512 f32 (2MB)

    prep_kernel<<<1, 256, 0, stream>>>(W0, b0, W1, b1, W2, b2, W01g, swp, sums);
    attstats_kernel<<<E_ / 256, 256, 0, stream>>>(coor, idx, geo, ang,
                                                  Wq, bq, Wk, bk, W01g,
                                                  D, P, M, part);
    reduce_kernel<<<32, 512, 0, stream>>>(part, sums);
    finalize_kernel<<<1, 256, 0, stream>>>(sums, gamma, beta, W2, W01g, folded);
    edge_kernel<<<N_ / 2, 256, 0, stream>>>(coor, folded, swp, D, P, M,
                                            (float*)d_out);
}

// Round 11
// 84.306 us; speedup vs baseline: 1.1131x; 1.1131x over previous
//
#include <hip/hip_runtime.h>

#define N_ 4096
#define K_ 64
#define E_ (N_*K_)
#define H_ 256
#define EPS_ 1e-5f
#define L2E_ 1.4426950408889634f   // log2(e)
#define TL2E_ 2.8853900817779268f  // 2*log2(e)

#if __has_builtin(__builtin_amdgcn_exp2f)
#define EXP2(x) __builtin_amdgcn_exp2f(x)
#else
#define EXP2(x) __expf((x) * 0.6931471805599453f)
#endif

// tanh(x) = 1 - 2/(2^(2*log2e*x)+1); inf-safe (exp2(+inf)->inf, rcp(inf)=0)
__device__ __forceinline__ float ftanh(float x) {
    float e = EXP2(x * TL2E_);
    return 1.0f - 2.0f * __builtin_amdgcn_rcpf(e + 1.0f);
}

// One block: W01g[5*256] = TL2E * {W0@W1 (4 rows); b0@W1 + b1};
// swp[0] = sum(W2)+b2; zeroes sums[512] for reduce's atomics.
__global__ __launch_bounds__(256) void prep_kernel(
    const float* __restrict__ W0, const float* __restrict__ b0,
    const float* __restrict__ W1, const float* __restrict__ b1,
    const float* __restrict__ W2, const float* __restrict__ b2,
    float* __restrict__ W01g, float* __restrict__ swp, float* __restrict__ sums)
{
    int c = threadIdx.x;
    float a0 = 0.f, a1 = 0.f, a2 = 0.f, a3 = 0.f, ab = 0.f;
    #pragma unroll 8
    for (int h = 0; h < H_; ++h) {
        float w = W1[h * H_ + c];
        a0 = fmaf(W0[h], w, a0);
        a1 = fmaf(W0[H_ + h], w, a1);
        a2 = fmaf(W0[2 * H_ + h], w, a2);
        a3 = fmaf(W0[3 * H_ + h], w, a3);
        ab = fmaf(b0[h], w, ab);
    }
    W01g[c]          = TL2E_ * a0;
    W01g[H_ + c]     = TL2E_ * a1;
    W01g[2 * H_ + c] = TL2E_ * a2;
    W01g[3 * H_ + c] = TL2E_ * a3;
    W01g[4 * H_ + c] = TL2E_ * (ab + b1[c]);
    sums[c] = 0.f;
    sums[H_ + c] = 0.f;

    __shared__ float red[256];
    red[c] = W2[c];
    __syncthreads();
    for (int s = 128; s > 0; s >>= 1) {
        if (c < s) red[c] += red[c + s];
        __syncthreads();
    }
    if (c == 0) swp[0] = red[0] + b2[0];
}

// Per-column partial sums of r = 1/(2^u+1) and r^2 over a 128-edge tile.
// Coalesced part[block][512] writes, no atomics. (R5-exact.)
__global__ __launch_bounds__(256, 8) void stats_kernel(
    const float* __restrict__ coor, const float* __restrict__ W01g,
    float* __restrict__ part)
{
    const int c = threadIdx.x;
    const float w0 = W01g[c],          w1 = W01g[H_ + c];
    const float w2 = W01g[2 * H_ + c], w3 = W01g[3 * H_ + c];
    const float bb = W01g[4 * H_ + c];
    __shared__ float4 T[128];
    const int e0 = blockIdx.x * 128;
    if (c < 128) {
        float4 v = reinterpret_cast<const float4*>(coor)[e0 + c];
        T[c] = make_float4(ftanh(v.x), ftanh(v.y), ftanh(v.z), ftanh(v.w));
    }
    __syncthreads();
    float sr = 0.f, sr2 = 0.f;
    #pragma unroll 8
    for (int i = 0; i < 128; ++i) {
        float4 t = T[i];
        float u = fmaf(t.w, w3, fmaf(t.z, w2, fmaf(t.y, w1, fmaf(t.x, w0, bb))));
        float r = __builtin_amdgcn_rcpf(EXP2(u) + 1.0f);
        sr += r;
        sr2 = fmaf(r, r, sr2);
    }
    part[blockIdx.x * 512 + c] = sr;
    part[blockIdx.x * 512 + 256 + c] = sr2;
}

// Row-wise coalesced reduce: 32 blocks x 512 threads, 64 rows each,
// one atomicAdd per thread (32-deep chains). (R5-exact.)
__global__ __launch_bounds__(512) void reduce_kernel(
    const float* __restrict__ part, float* __restrict__ sums)
{
    int t = threadIdx.x;
    int b0 = blockIdx.x * 64;
    float local = 0.f;
    #pragma unroll 8
    for (int b = b0; b < b0 + 64; ++b) local += part[b * 512 + t];
    atomicAdd(&sums[t], local);
}

// Fold BN+weights into per-column record, exp2-prescaled. (R5-exact.)
__global__ __launch_bounds__(256) void finalize_kernel(
    const float* __restrict__ sums, const float* __restrict__ gamma,
    const float* __restrict__ beta, const float* __restrict__ W2,
    const float* __restrict__ W01g, float* __restrict__ folded)
{
    int c = threadIdx.x;
    const float inv = 1.0f / (float)E_;
    float sp = sums[c] * inv;
    float sq = sums[256 + c] * inv;
    float mu = 1.0f - 2.0f * sp;            // mean of h = 1-2r
    float var = 4.0f * fmaf(-sp, sp, sq);
    float a  = gamma[c] * rsqrtf(var + EPS_);
    float bf = fmaf(-mu, a, beta[c]);
    folded[8 * c + 0] = W01g[c];
    folded[8 * c + 1] = W01g[H_ + c];
    folded[8 * c + 2] = W01g[2 * H_ + c];
    folded[8 * c + 3] = W01g[3 * H_ + c];
    folded[8 * c + 4] = W01g[4 * H_ + c];
    folded[8 * c + 5] = -4.0f * L2E_ * a;   // coeff of r
    folded[8 * c + 6] = TL2E_ * (a + bf);   // const term
    folded[8 * c + 7] = -2.0f * W2[c];      // acc coeff on r2
}

// Edge kernel: R5-exact staging/compute/zero-fill; att+col moved to stage
// (registers persist to tail); tail dedup via LDS-broadcast float4 compares
// (no serial shfl chain) + rare-dup mask walk.
__global__ __launch_bounds__(256, 8) void edge_kernel(
    const float* __restrict__ coor, const int* __restrict__ idx,
    const float* __restrict__ folded, const float* __restrict__ swp,
    const float* __restrict__ Wq, const float* __restrict__ bq,
    const float* __restrict__ Wk, const float* __restrict__ bk,
    const float* __restrict__ geo, const float* __restrict__ ang,
    float* __restrict__ out)
{
    __shared__ float4 FS[2 * H_];   // folded per-column records (8KB)
    __shared__ float4 TS[128];      // per-edge tanh quads (2KB)
    __shared__ float  ACC[8][128];  // chunk x edge partial accs (4KB)
    __shared__ int    COL[128];     // per-edge col (512B)
    __shared__ float  ATT[128];     // per-edge |att| (512B)

    const int t = threadIdx.x;
    const int row0 = blockIdx.x * 2;
    const int eb0 = blockIdx.x * 128;

    {
        const float4* F = reinterpret_cast<const float4*>(folded);
        FS[t] = F[t];
        FS[t + 256] = F[t + 256];
    }
    int col = 0;
    float att = 0.f;
    if (t < 128) {
        float4 ce = reinterpret_cast<const float4*>(coor)[eb0 + t];
        TS[t] = make_float4(ftanh(ce.x), ftanh(ce.y), ftanh(ce.z), ftanh(ce.w));
        col = idx[E_ + eb0 + t];
        float ex = ce.x + ce.z, ey = ce.y + ce.w;
        float sx = __shfl(ex, 0), sy = __shfl(ey, 0);  // wave = row here
        #pragma unroll
        for (int j = 0; j < 8; ++j) {
            float qj = fmaf(sy, Wq[8 + j], fmaf(sx, Wq[j], bq[j]));
            float kj = fmaf(ey, Wk[8 + j], fmaf(ex, Wk[j], bk[j]));
            att = fmaf(qj, kj, att);
        }
        att = fabsf(att);
        COL[t] = col;
        ATT[t] = att;
    }
    {   // zero-fill this block's 2 rows (replaces 64MB memset); R5 position
        float4 z = make_float4(0.f, 0.f, 0.f, 0.f);
        float4* orow = reinterpret_cast<float4*>(out + (size_t)row0 * N_);
        #pragma unroll
        for (int i = 0; i < 8; ++i) orow[i * 256 + t] = z;
    }
    __syncthreads();

    // ---- compute: 4 edges x 32 columns per thread (R5-exact) ----
    const int eg = (t & 31) * 4;
    const int chunk = t >> 5;
    const float4 tq0 = TS[eg], tq1 = TS[eg + 1], tq2 = TS[eg + 2], tq3 = TS[eg + 3];
    const float4* Fp = &FS[chunk * 64];
    float a0 = 0.f, a1 = 0.f, a2 = 0.f, a3 = 0.f;
    #pragma unroll 4
    for (int i = 0; i < 32; ++i) {
        float4 f0 = Fp[2 * i];
        float4 f1 = Fp[2 * i + 1];
        #define EVAL(tq, ak) { \
            float u = fmaf(tq.w, f0.w, fmaf(tq.z, f0.z, fmaf(tq.y, f0.y, fmaf(tq.x, f0.x, f1.x)))); \
            float r = __builtin_amdgcn_rcpf(EXP2(u) + 1.0f); \
            float r2 = __builtin_amdgcn_rcpf(EXP2(fmaf(r, f1.y, f1.z)) + 1.0f); \
            ak = fmaf(r2, f1.w, ak); }
        EVAL(tq0, a0) EVAL(tq1, a1) EVAL(tq2, a2) EVAL(tq3, a3)
        #undef EVAL
    }
    *reinterpret_cast<float4*>(&ACC[chunk][eg]) = make_float4(a0, a1, a2, a3);
    __syncthreads();

    // ---- write phase: waves 0,1 (wave = row) ----
    const int w = t >> 6, lane = t & 63;
    if (w < 2) {
        float val = swp[0];
        #pragma unroll
        for (int c = 0; c < 8; ++c) val += ACC[c][t];
        val = fmaxf(val, 0.f);

        // dedup mask + asum via broadcast float4 LDS reads (no shfl chain)
        const int rb = w * 64;
        unsigned long long m = 0;
        float asum = 0.f;
        #pragma unroll 8
        for (int j4 = 0; j4 < 16; ++j4) {
            int4   c4 = *reinterpret_cast<const int4*>(&COL[rb + 4 * j4]);
            float4 a4 = *reinterpret_cast<const float4*>(&ATT[rb + 4 * j4]);
            m |= (unsigned long long)(c4.x == col) << (4 * j4 + 0);
            m |= (unsigned long long)(c4.y == col) << (4 * j4 + 1);
            m |= (unsigned long long)(c4.z == col) << (4 * j4 + 2);
            m |= (unsigned long long)(c4.w == col) << (4 * j4 + 3);
            asum += (c4.x == col) ? a4.x : 0.f;
            asum += (c4.y == col) ? a4.y : 0.f;
            asum += (c4.z == col) ? a4.z : 0.f;
            asum += (c4.w == col) ? a4.w : 0.f;
        }
        bool leader = ((m & ((1ull << lane) - 1ull)) == 0ull);

        // rare-dup vsum: walk mask (excl self); all lanes active for shfl
        float vsum = val;
        unsigned long long m2 = m & ~(1ull << lane);
        while (__any(m2 != 0ull)) {
            unsigned long long pick = m2 ? m2 : 1ull;
            int j = __ffsll(pick) - 1;
            float bv = __shfl(val, j);
            if (m2) { vsum += bv; m2 &= m2 - 1; }
        }
        if (leader) {
            size_t p = (size_t)(row0 + w) * N_ + col;
            out[p] = vsum * __expf(-asum * geo[p]) * ang[p];
        }
    }
}

extern "C" void kernel_launch(void* const* d_in, const int* in_sizes, int n_in,
                              void* d_out, int out_size, void* d_ws, size_t ws_size,
                              hipStream_t stream)
{
    const float* coor  = (const float*)d_in[1];
    const int*   idx   = (const int*)d_in[2];
    const float* geo   = (const float*)d_in[3];
    const float* ang   = (const float*)d_in[4];
    const float* W0    = (const float*)d_in[5];
    const float* b0    = (const float*)d_in[6];
    const float* W1    = (const float*)d_in[7];
    const float* b1    = (const float*)d_in[8];
    const float* gamma = (const float*)d_in[9];
    const float* beta  = (const float*)d_in[10];
    const float* W2    = (const float*)d_in[11];
    const float* b2    = (const float*)d_in[12];
    const float* Wq    = (const float*)d_in[13];
    const float* bq    = (const float*)d_in[14];
    const float* Wk    = (const float*)d_in[15];
    const float* bk    = (const float*)d_in[16];

    char* ws = (char*)d_ws;
    float* swp    = (float*)ws;            // 1
    float* sums   = (float*)(ws + 1024);   // 512
    float* W01g   = (float*)(ws + 4096);   // 1280
    float* folded = (float*)(ws + 10240);  // 2048
    float* part   = (float*)(ws + 20480);  // 2048*512 floats (4 MB)

    prep_kernel<<<1, 256, 0, stream>>>(W0, b0, W1, b1, W2, b2, W01g, swp, sums);
    stats_kernel<<<E_ / 128, 256, 0, stream>>>(coor, W01g, part);
    reduce_kernel<<<32, 512, 0, stream>>>(part, sums);
    finalize_kernel<<<1, 256, 0, stream>>>(sums, gamma, beta, W2, W01g, folded);
    edge_kernel<<<N_ / 2, 256, 0, stream>>>(coor, idx, folded, swp,
                                            Wq, bq, Wk, bk, geo, ang, (float*)d_out);
}

// Round 12
// 76.382 us; speedup vs baseline: 1.2286x; 1.1037x over previous
//
#include <hip/hip_runtime.h>

#define N_ 4096
#define K_ 64
#define E_ (N_*K_)
#define H_ 256
#define EPS_ 1e-5f
#define L2E_ 1.4426950408889634f   // log2(e)
#define TL2E_ 2.8853900817779268f  // 2*log2(e)

#if __has_builtin(__builtin_amdgcn_exp2f)
#define EXP2(x) __builtin_amdgcn_exp2f(x)
#else
#define EXP2(x) __expf((x) * 0.6931471805599453f)
#endif

// tanh(x) = 1 - 2/(2^(2*log2e*x)+1); inf-safe (exp2(+inf)->inf, rcp(inf)=0)
__device__ __forceinline__ float ftanh(float x) {
    float e = EXP2(x * TL2E_);
    return 1.0f - 2.0f * __builtin_amdgcn_rcpf(e + 1.0f);
}

// R5-exact: W01 = W0 @ W1 (4x256), b01 = b0 @ W1 (+ b1). 32 blocks x 8 h-rows,
// atomic accumulate (32-deep chains, cheap). W01/b01 pre-zeroed by ws memset.
__global__ __launch_bounds__(256) void prep_kernel(
    const float* __restrict__ W0, const float* __restrict__ b0,
    const float* __restrict__ W1, const float* __restrict__ b1,
    float* __restrict__ W01, float* __restrict__ b01)
{
    int c = threadIdx.x;
    int h0 = blockIdx.x * 8;
    float a0 = 0.f, a1 = 0.f, a2 = 0.f, a3 = 0.f, ab = 0.f;
    #pragma unroll
    for (int h = h0; h < h0 + 8; ++h) {
        float w = W1[h * H_ + c];
        a0 = fmaf(W0[0 * H_ + h], w, a0);
        a1 = fmaf(W0[1 * H_ + h], w, a1);
        a2 = fmaf(W0[2 * H_ + h], w, a2);
        a3 = fmaf(W0[3 * H_ + h], w, a3);
        ab = fmaf(b0[h], w, ab);
    }
    if (blockIdx.x == 0) ab += b1[c];
    atomicAdd(&W01[c], a0);
    atomicAdd(&W01[H_ + c], a1);
    atomicAdd(&W01[2 * H_ + c], a2);
    atomicAdd(&W01[3 * H_ + c], a3);
    atomicAdd(&b01[c], ab);
}

// R5-exact stats: per-column partial sums of r, r^2 over a 128-edge tile.
__global__ __launch_bounds__(256, 8) void stats_kernel(
    const float* __restrict__ coor, const float* __restrict__ W01,
    const float* __restrict__ b01, float* __restrict__ part)
{
    const int c = threadIdx.x;
    const float w0 = TL2E_ * W01[c],        w1 = TL2E_ * W01[H_ + c];
    const float w2 = TL2E_ * W01[2*H_ + c], w3 = TL2E_ * W01[3*H_ + c];
    const float bb = TL2E_ * b01[c];
    __shared__ float4 T[128];
    const int e0 = blockIdx.x * 128;
    if (c < 128) {
        float4 v = reinterpret_cast<const float4*>(coor)[e0 + c];
        T[c] = make_float4(ftanh(v.x), ftanh(v.y), ftanh(v.z), ftanh(v.w));
    }
    __syncthreads();
    float sr = 0.f, sr2 = 0.f;
    #pragma unroll 8
    for (int i = 0; i < 128; ++i) {
        float4 t = T[i];
        float u = fmaf(t.w, w3, fmaf(t.z, w2, fmaf(t.y, w1, fmaf(t.x, w0, bb))));
        float r = __builtin_amdgcn_rcpf(EXP2(u) + 1.0f);
        sr += r;
        sr2 = fmaf(r, r, sr2);
    }
    part[blockIdx.x * 512 + c] = sr;
    part[blockIdx.x * 512 + 256 + c] = sr2;
}

// R5-exact reduce: 32 blocks x 512 threads, row-wise coalesced.
__global__ __launch_bounds__(512) void reduce_kernel(
    const float* __restrict__ part, float* __restrict__ sums)
{
    int t = threadIdx.x;
    int b0 = blockIdx.x * 64;
    float local = 0.f;
    #pragma unroll 8
    for (int b = b0; b < b0 + 64; ++b) local += part[b * 512 + t];
    atomicAdd(&sums[t], local);
}

// R5-exact finalize: fold BN+weights into per-column record; swp = sum(W2)+b2.
__global__ __launch_bounds__(256) void finalize_kernel(
    const float* __restrict__ sums, const float* __restrict__ gamma,
    const float* __restrict__ beta, const float* __restrict__ W2,
    const float* __restrict__ b2,
    const float* __restrict__ W01, const float* __restrict__ b01,
    float* __restrict__ folded, float* __restrict__ swp)
{
    int c = threadIdx.x;
    const float inv = 1.0f / (float)E_;
    float p = sums[c] * inv;
    float q = sums[256 + c] * inv;
    float mu = 1.0f - 2.0f * p;
    float var = 4.0f * fmaf(-p, p, q);
    float a = gamma[c] * rsqrtf(var + EPS_);
    float bf = fmaf(-mu, a, beta[c]);
    folded[c * 8 + 0] = TL2E_ * W01[c];
    folded[c * 8 + 1] = TL2E_ * W01[H_ + c];
    folded[c * 8 + 2] = TL2E_ * W01[2 * H_ + c];
    folded[c * 8 + 3] = TL2E_ * W01[3 * H_ + c];
    folded[c * 8 + 4] = TL2E_ * b01[c];
    folded[c * 8 + 5] = -4.0f * L2E_ * a;
    folded[c * 8 + 6] = TL2E_ * (a + bf);
    folded[c * 8 + 7] = -2.0f * W2[c];
    __shared__ float red[256];
    red[c] = W2[c];
    __syncthreads();
    for (int s = 128; s > 0; s >>= 1) {
        if (c < s) red[c] += red[c + s];
        __syncthreads();
    }
    if (c == 0) swp[0] = red[0] + b2[0];
}

// Edge kernel. ONE change vs measured-44.5us structure: compute phase uses
// 8 independent chains/thread (8 edges x 16 cols; SoA tanh; FS padded +1/16
// cols so the 16 chunk bases hit banks {0,4,8,12} = conflict-free).
// Tail: LDS-compare dedup (R11, measured equal) + hoisted geo/ang loads.
__global__ __launch_bounds__(256, 8) void edge_kernel(
    const float* __restrict__ coor, const int* __restrict__ idx,
    const float* __restrict__ folded, const float* __restrict__ swp,
    const float* __restrict__ Wq, const float* __restrict__ bq,
    const float* __restrict__ Wk, const float* __restrict__ bk,
    const float* __restrict__ geo, const float* __restrict__ ang,
    float* __restrict__ out)
{
    __shared__ float4 FS[2 * H_ + 16];  // padded: col c at 2c+(c>>4)
    __shared__ float  TSx[128], TSy[128], TSz[128], TSw[128];
    __shared__ float  ACC[16][128];     // chunk x edge partials (8KB)
    __shared__ int    COL[128];
    __shared__ float  ATT[128];

    const int t = threadIdx.x;
    const int row0 = blockIdx.x * 2;
    const int eb0 = blockIdx.x * 128;

    {   // stage folded with pad swizzle: FS[j + (j>>5)] = F[j]
        const float4* F = reinterpret_cast<const float4*>(folded);
        FS[t + (t >> 5)] = F[t];
        int j = t + 256;
        FS[j + (j >> 5)] = F[j];
    }
    int col = 0;
    if (t < 128) {
        float4 ce = reinterpret_cast<const float4*>(coor)[eb0 + t];
        TSx[t] = ftanh(ce.x); TSy[t] = ftanh(ce.y);
        TSz[t] = ftanh(ce.z); TSw[t] = ftanh(ce.w);
        col = idx[E_ + eb0 + t];
        float ex = ce.x + ce.z, ey = ce.y + ce.w;
        float sx = __shfl(ex, 0), sy = __shfl(ey, 0);  // wave = row here
        float att = 0.f;
        #pragma unroll
        for (int j = 0; j < 8; ++j) {
            float qj = fmaf(sy, Wq[8 + j], fmaf(sx, Wq[j], bq[j]));
            float kj = fmaf(ey, Wk[8 + j], fmaf(ex, Wk[j], bk[j]));
            att = fmaf(qj, kj, att);
        }
        COL[t] = col;
        ATT[t] = fabsf(att);
    }
    {   // zero-fill this block's 2 rows (replaces 64MB memset); R5 position
        float4 z = make_float4(0.f, 0.f, 0.f, 0.f);
        float4* orow = reinterpret_cast<float4*>(out + (size_t)row0 * N_);
        #pragma unroll
        for (int i = 0; i < 8; ++i) orow[i * 256 + t] = z;
    }
    __syncthreads();

    // ---- compute: 8 edges x 16 columns per thread (8 indep chains) ----
    const int eg = (t & 15) * 8;
    const int chunk = t >> 4;           // 0..15
    float4 xa = *reinterpret_cast<const float4*>(&TSx[eg]);
    float4 xb = *reinterpret_cast<const float4*>(&TSx[eg + 4]);
    float4 ya = *reinterpret_cast<const float4*>(&TSy[eg]);
    float4 yb = *reinterpret_cast<const float4*>(&TSy[eg + 4]);
    float4 za = *reinterpret_cast<const float4*>(&TSz[eg]);
    float4 zb = *reinterpret_cast<const float4*>(&TSz[eg + 4]);
    float4 wa = *reinterpret_cast<const float4*>(&TSw[eg]);
    float4 wb = *reinterpret_cast<const float4*>(&TSw[eg + 4]);
    const float4* Fp = &FS[chunk * 33];  // 33 float4 = 528B stride: banks 0,4,8,12
    float ac0 = 0.f, ac1 = 0.f, ac2 = 0.f, ac3 = 0.f;
    float ac4 = 0.f, ac5 = 0.f, ac6 = 0.f, ac7 = 0.f;
    #define EVAL(tx_, ty_, tz_, tw_, ak) { \
        float u = fmaf(tw_, f0.w, fmaf(tz_, f0.z, fmaf(ty_, f0.y, fmaf(tx_, f0.x, f1.x)))); \
        float r = __builtin_amdgcn_rcpf(EXP2(u) + 1.0f); \
        float r2 = __builtin_amdgcn_rcpf(EXP2(fmaf(r, f1.y, f1.z)) + 1.0f); \
        ak = fmaf(r2, f1.w, ak); }
    #pragma unroll 4
    for (int i = 0; i < 16; ++i) {
        float4 f0 = Fp[2 * i];
        float4 f1 = Fp[2 * i + 1];
        EVAL(xa.x, ya.x, za.x, wa.x, ac0)
        EVAL(xa.y, ya.y, za.y, wa.y, ac1)
        EVAL(xa.z, ya.z, za.z, wa.z, ac2)
        EVAL(xa.w, ya.w, za.w, wa.w, ac3)
        EVAL(xb.x, yb.x, zb.x, wb.x, ac4)
        EVAL(xb.y, yb.y, zb.y, wb.y, ac5)
        EVAL(xb.z, yb.z, zb.z, wb.z, ac6)
        EVAL(xb.w, yb.w, zb.w, wb.w, ac7)
    }
    #undef EVAL
    *reinterpret_cast<float4*>(&ACC[chunk][eg])     = make_float4(ac0, ac1, ac2, ac3);
    *reinterpret_cast<float4*>(&ACC[chunk][eg + 4]) = make_float4(ac4, ac5, ac6, ac7);
    __syncthreads();

    // ---- write phase: waves 0,1 (wave = row) ----
    const int w = t >> 6, lane = t & 63;
    if (w < 2) {
        float val = swp[0];
        #pragma unroll
        for (int c = 0; c < 16; ++c) val += ACC[c][t];
        val = fmaxf(val, 0.f);

        // hoisted gather: independent of dedup loop, latency overlaps it
        size_t p = (size_t)(row0 + w) * N_ + col;
        float g = geo[p], an = ang[p];

        // dedup mask + asum via broadcast float4 LDS reads
        const int rb = w * 64;
        unsigned long long m = 0;
        float asum = 0.f;
        #pragma unroll 8
        for (int j4 = 0; j4 < 16; ++j4) {
            int4   c4 = *reinterpret_cast<const int4*>(&COL[rb + 4 * j4]);
            float4 a4 = *reinterpret_cast<const float4*>(&ATT[rb + 4 * j4]);
            m |= (unsigned long long)(c4.x == col) << (4 * j4 + 0);
            m |= (unsigned long long)(c4.y == col) << (4 * j4 + 1);
            m |= (unsigned long long)(c4.z == col) << (4 * j4 + 2);
            m |= (unsigned long long)(c4.w == col) << (4 * j4 + 3);
            asum += (c4.x == col) ? a4.x : 0.f;
            asum += (c4.y == col) ? a4.y : 0.f;
            asum += (c4.z == col) ? a4.z : 0.f;
            asum += (c4.w == col) ? a4.w : 0.f;
        }
        bool leader = ((m & ((1ull << lane) - 1ull)) == 0ull);

        // rare-dup vsum: walk mask (excl self); all lanes active for shfl
        float vsum = val;
        unsigned long long m2 = m & ~(1ull << lane);
        while (__any(m2 != 0ull)) {
            unsigned long long pick = m2 ? m2 : 1ull;
            int j = __ffsll(pick) - 1;
            float bv = __shfl(val, j);
            if (m2) { vsum += bv; m2 &= m2 - 1; }
        }
        if (leader) {
            out[p] = vsum * __expf(-asum * g) * an;
        }
    }
}

extern "C" void kernel_launch(void* const* d_in, const int* in_sizes, int n_in,
                              void* d_out, int out_size, void* d_ws, size_t ws_size,
                              hipStream_t stream)
{
    const float* coor  = (const float*)d_in[1];
    const int*   idx   = (const int*)d_in[2];
    const float* geo   = (const float*)d_in[3];
    const float* ang   = (const float*)d_in[4];
    const float* W0    = (const float*)d_in[5];
    const float* b0    = (const float*)d_in[6];
    const float* W1    = (const float*)d_in[7];
    const float* b1    = (const float*)d_in[8];
    const float* gamma = (const float*)d_in[9];
    const float* beta  = (const float*)d_in[10];
    const float* W2    = (const float*)d_in[11];
    const float* b2    = (const float*)d_in[12];
    const float* Wq    = (const float*)d_in[13];
    const float* bq    = (const float*)d_in[14];
    const float* Wk    = (const float*)d_in[15];
    const float* bk    = (const float*)d_in[16];

    float* ws = (float*)d_ws;
    float* sums   = ws;            // 512
    float* W01    = ws + 512;      // 1024
    float* b01    = ws + 1536;     // 256
    float* folded = ws + 1792;     // 2048
    float* swp    = ws + 3840;     // 1
    float* part   = ws + 4096;     // 2048*512 floats (4 MB)

    hipMemsetAsync(ws, 0, 1792 * sizeof(float), stream);  // sums + W01 + b01

    prep_kernel<<<32, 256, 0, stream>>>(W0, b0, W1, b1, W01, b01);
    stats_kernel<<<E_ / 128, 256, 0, stream>>>(coor, W01, b01, part);
    reduce_kernel<<<32, 512, 0, stream>>>(part, sums);
    finalize_kernel<<<1, 256, 0, stream>>>(sums, gamma, beta, W2, b2, W01, b01,
                                           folded, swp);
    edge_kernel<<<N_ / 2, 256, 0, stream>>>(coor, idx, folded, swp,
                                            Wq, bq, Wk, bk, geo, ang, (float*)d_out);
}

// Round 13
// 69.748 us; speedup vs baseline: 1.3454x; 1.0951x over previous
//
#include <hip/hip_runtime.h>

#define N_ 4096
#define K_ 64
#define E_ (N_*K_)
#define H_ 256
#define EPS_ 1e-5f
#define L2E_ 1.4426950408889634f   // log2(e)
#define TL2E_ 2.8853900817779268f  // 2*log2(e)

#if __has_builtin(__builtin_amdgcn_exp2f)
#define EXP2(x) __builtin_amdgcn_exp2f(x)
#else
#define EXP2(x) __expf((x) * 0.6931471805599453f)
#endif

// tanh(x) = 1 - 2/(2^(2*log2e*x)+1); inf-safe (exp2(+inf)->inf, rcp(inf)=0)
__device__ __forceinline__ float ftanh(float x) {
    float e = EXP2(x * TL2E_);
    return 1.0f - 2.0f * __builtin_amdgcn_rcpf(e + 1.0f);
}

// prep2: 8 blocks x 32-col slices. LDS-tiled W1 (coalesced float4), no atomics,
// no memset. W01g[5*256] = TL2E*{W0@W1; b0@W1+b1}. Block 0: swp = sum(W2)+b2.
// All blocks zero their slice of part[32][512].
__global__ __launch_bounds__(256) void prep2_kernel(
    const float* __restrict__ W0, const float* __restrict__ b0,
    const float* __restrict__ W1, const float* __restrict__ b1,
    const float* __restrict__ W2, const float* __restrict__ b2,
    float* __restrict__ W01g, float* __restrict__ swp, float* __restrict__ part)
{
    __shared__ float LW1[256 * 32];   // [h][c_loc], 32 KB
    __shared__ float W0s[5 * 256];    // W0 rows 0..3 + b0
    __shared__ float red[256];

    const int t = threadIdx.x;
    const int b = blockIdx.x;

    // zero this block's slice of part (16384 floats / 8 blocks = 2048)
    #pragma unroll
    for (int k = 0; k < 8; ++k) part[b * 2048 + k * 256 + t] = 0.f;

    // load W1 tile: cols [b*32, b*32+32), 2048 float4, 8 per thread
    {
        const float4* W1_4 = reinterpret_cast<const float4*>(W1);
        #pragma unroll
        for (int k = 0; k < 8; ++k) {
            int flat = k * 256 + t;           // float4 index in tile
            int h = flat >> 3, j = flat & 7;  // row, col-quad
            *reinterpret_cast<float4*>(&LW1[h * 32 + 4 * j]) = W1_4[h * 64 + b * 8 + j];
        }
        W0s[t] = W0[t];
        W0s[256 + t] = W0[256 + t];
        W0s[512 + t] = W0[512 + t];
        W0s[768 + t] = W0[768 + t];
        W0s[1024 + t] = b0[t];
        red[t] = W2[t];
    }
    __syncthreads();

    // compute: role = t>>5 (0..7), c = t&31. roles 0-3: W0 row dot; 4: b0 dot.
    const int role = t >> 5, c = t & 31;
    if (role < 5) {
        const float* wrow = &W0s[role * 256];   // role 4 -> b0s
        float acc = 0.f;
        #pragma unroll 8
        for (int h = 0; h < 256; ++h) acc = fmaf(wrow[h], LW1[h * 32 + c], acc);
        int cg = b * 32 + c;
        if (role < 4) W01g[role * 256 + cg] = TL2E_ * acc;
        else          W01g[1024 + cg] = TL2E_ * (acc + b1[cg]);
    }

    if (b == 0) {
        __syncthreads();
        for (int s = 128; s > 0; s >>= 1) {
            if (t < s) red[t] += red[t + s];
            __syncthreads();
        }
        if (t == 0) swp[0] = red[0] + b2[0];
    }
}

// stats: R12 core (W01g prescaled); tail = grouped atomicAdd into
// part[blockIdx&31][col] (64-deep chains, replaces reduce dispatch).
__global__ __launch_bounds__(256, 8) void stats_kernel(
    const float* __restrict__ coor, const float* __restrict__ W01g,
    float* __restrict__ part)
{
    const int c = threadIdx.x;
    const float w0 = W01g[c],          w1 = W01g[H_ + c];
    const float w2 = W01g[2 * H_ + c], w3 = W01g[3 * H_ + c];
    const float bb = W01g[4 * H_ + c];
    __shared__ float4 T[128];
    const int e0 = blockIdx.x * 128;
    if (c < 128) {
        float4 v = reinterpret_cast<const float4*>(coor)[e0 + c];
        T[c] = make_float4(ftanh(v.x), ftanh(v.y), ftanh(v.z), ftanh(v.w));
    }
    __syncthreads();
    float sr = 0.f, sr2 = 0.f;
    #pragma unroll 8
    for (int i = 0; i < 128; ++i) {
        float4 t = T[i];
        float u = fmaf(t.w, w3, fmaf(t.z, w2, fmaf(t.y, w1, fmaf(t.x, w0, bb))));
        float r = __builtin_amdgcn_rcpf(EXP2(u) + 1.0f);
        sr += r;
        sr2 = fmaf(r, r, sr2);
    }
    const int g = blockIdx.x & 31;
    atomicAdd(&part[g * 512 + c], sr);
    atomicAdd(&part[g * 512 + 256 + c], sr2);
}

// Edge kernel: R12 compute/tail exact. Stage: reduce part (32 groups, coalesced
// L2-hot) + BN-fold directly into FS (replaces finalize + folded round-trip).
__global__ __launch_bounds__(256, 8) void edge_kernel(
    const float* __restrict__ coor, const int* __restrict__ idx,
    const float* __restrict__ part, const float* __restrict__ W01g,
    const float* __restrict__ gamma, const float* __restrict__ beta,
    const float* __restrict__ W2, const float* __restrict__ swp,
    const float* __restrict__ Wq, const float* __restrict__ bq,
    const float* __restrict__ Wk, const float* __restrict__ bk,
    const float* __restrict__ geo, const float* __restrict__ ang,
    float* __restrict__ out)
{
    __shared__ float4 FS[2 * H_ + 16];  // padded: col c at 2c+(c>>4)
    __shared__ float  TSx[128], TSy[128], TSz[128], TSw[128];
    __shared__ float  ACC[16][128];
    __shared__ int    COL[128];
    __shared__ float  ATT[128];

    const int t = threadIdx.x;
    const int row0 = blockIdx.x * 2;
    const int eb0 = blockIdx.x * 128;

    // ---- stage: reduce part -> BN-fold column t -> FS (padded layout) ----
    {
        float sr = 0.f, sr2 = 0.f;
        #pragma unroll 8
        for (int g = 0; g < 32; ++g) {
            sr  += part[g * 512 + t];
            sr2 += part[g * 512 + 256 + t];
        }
        const float inv = 1.0f / (float)E_;
        float sp = sr * inv;
        float sq = sr2 * inv;
        float mu = 1.0f - 2.0f * sp;
        float var = 4.0f * fmaf(-sp, sp, sq);
        float a  = gamma[t] * rsqrtf(var + EPS_);
        float bf = fmaf(-mu, a, beta[t]);
        int base = 2 * t + (t >> 4);
        FS[base]     = make_float4(W01g[t], W01g[H_ + t], W01g[2 * H_ + t], W01g[3 * H_ + t]);
        FS[base + 1] = make_float4(W01g[4 * H_ + t], -4.0f * L2E_ * a,
                                   TL2E_ * (a + bf), -2.0f * W2[t]);
    }
    int col = 0;
    if (t < 128) {
        float4 ce = reinterpret_cast<const float4*>(coor)[eb0 + t];
        TSx[t] = ftanh(ce.x); TSy[t] = ftanh(ce.y);
        TSz[t] = ftanh(ce.z); TSw[t] = ftanh(ce.w);
        col = idx[E_ + eb0 + t];
        float ex = ce.x + ce.z, ey = ce.y + ce.w;
        float sx = __shfl(ex, 0), sy = __shfl(ey, 0);  // wave = row here
        float att = 0.f;
        #pragma unroll
        for (int j = 0; j < 8; ++j) {
            float qj = fmaf(sy, Wq[8 + j], fmaf(sx, Wq[j], bq[j]));
            float kj = fmaf(ey, Wk[8 + j], fmaf(ex, Wk[j], bk[j]));
            att = fmaf(qj, kj, att);
        }
        COL[t] = col;
        ATT[t] = fabsf(att);
    }
    {   // zero-fill this block's 2 rows (replaces 64MB memset)
        float4 z = make_float4(0.f, 0.f, 0.f, 0.f);
        float4* orow = reinterpret_cast<float4*>(out + (size_t)row0 * N_);
        #pragma unroll
        for (int i = 0; i < 8; ++i) orow[i * 256 + t] = z;
    }
    __syncthreads();

    // ---- compute: 8 edges x 16 columns per thread (R12-exact) ----
    const int eg = (t & 15) * 8;
    const int chunk = t >> 4;           // 0..15
    float4 xa = *reinterpret_cast<const float4*>(&TSx[eg]);
    float4 xb = *reinterpret_cast<const float4*>(&TSx[eg + 4]);
    float4 ya = *reinterpret_cast<const float4*>(&TSy[eg]);
    float4 yb = *reinterpret_cast<const float4*>(&TSy[eg + 4]);
    float4 za = *reinterpret_cast<const float4*>(&TSz[eg]);
    float4 zb = *reinterpret_cast<const float4*>(&TSz[eg + 4]);
    float4 wa = *reinterpret_cast<const float4*>(&TSw[eg]);
    float4 wb = *reinterpret_cast<const float4*>(&TSw[eg + 4]);
    const float4* Fp = &FS[chunk * 33];
    float ac0 = 0.f, ac1 = 0.f, ac2 = 0.f, ac3 = 0.f;
    float ac4 = 0.f, ac5 = 0.f, ac6 = 0.f, ac7 = 0.f;
    #define EVAL(tx_, ty_, tz_, tw_, ak) { \
        float u = fmaf(tw_, f0.w, fmaf(tz_, f0.z, fmaf(ty_, f0.y, fmaf(tx_, f0.x, f1.x)))); \
        float r = __builtin_amdgcn_rcpf(EXP2(u) + 1.0f); \
        float r2 = __builtin_amdgcn_rcpf(EXP2(fmaf(r, f1.y, f1.z)) + 1.0f); \
        ak = fmaf(r2, f1.w, ak); }
    #pragma unroll 4
    for (int i = 0; i < 16; ++i) {
        float4 f0 = Fp[2 * i];
        float4 f1 = Fp[2 * i + 1];
        EVAL(xa.x, ya.x, za.x, wa.x, ac0)
        EVAL(xa.y, ya.y, za.y, wa.y, ac1)
        EVAL(xa.z, ya.z, za.z, wa.z, ac2)
        EVAL(xa.w, ya.w, za.w, wa.w, ac3)
        EVAL(xb.x, yb.x, zb.x, wb.x, ac4)
        EVAL(xb.y, yb.y, zb.y, wb.y, ac5)
        EVAL(xb.z, yb.z, zb.z, wb.z, ac6)
        EVAL(xb.w, yb.w, zb.w, wb.w, ac7)
    }
    #undef EVAL
    *reinterpret_cast<float4*>(&ACC[chunk][eg])     = make_float4(ac0, ac1, ac2, ac3);
    *reinterpret_cast<float4*>(&ACC[chunk][eg + 4]) = make_float4(ac4, ac5, ac6, ac7);
    __syncthreads();

    // ---- write phase: waves 0,1 (wave = row), R12-exact ----
    const int w = t >> 6, lane = t & 63;
    if (w < 2) {
        float val = swp[0];
        #pragma unroll
        for (int c = 0; c < 16; ++c) val += ACC[c][t];
        val = fmaxf(val, 0.f);

        size_t p = (size_t)(row0 + w) * N_ + col;
        float g = geo[p], an = ang[p];

        const int rb = w * 64;
        unsigned long long m = 0;
        float asum = 0.f;
        #pragma unroll 8
        for (int j4 = 0; j4 < 16; ++j4) {
            int4   c4 = *reinterpret_cast<const int4*>(&COL[rb + 4 * j4]);
            float4 a4 = *reinterpret_cast<const float4*>(&ATT[rb + 4 * j4]);
            m |= (unsigned long long)(c4.x == col) << (4 * j4 + 0);
            m |= (unsigned long long)(c4.y == col) << (4 * j4 + 1);
            m |= (unsigned long long)(c4.z == col) << (4 * j4 + 2);
            m |= (unsigned long long)(c4.w == col) << (4 * j4 + 3);
            asum += (c4.x == col) ? a4.x : 0.f;
            asum += (c4.y == col) ? a4.y : 0.f;
            asum += (c4.z == col) ? a4.z : 0.f;
            asum += (c4.w == col) ? a4.w : 0.f;
        }
        bool leader = ((m & ((1ull << lane) - 1ull)) == 0ull);

        float vsum = val;
        unsigned long long m2 = m & ~(1ull << lane);
        while (__any(m2 != 0ull)) {
            unsigned long long pick = m2 ? m2 : 1ull;
            int j = __ffsll(pick) - 1;
            float bv = __shfl(val, j);
            if (m2) { vsum += bv; m2 &= m2 - 1; }
        }
        if (leader) {
            out[p] = vsum * __expf(-asum * g) * an;
        }
    }
}

extern "C" void kernel_launch(void* const* d_in, const int* in_sizes, int n_in,
                              void* d_out, int out_size, void* d_ws, size_t ws_size,
                              hipStream_t stream)
{
    const float* coor  = (const float*)d_in[1];
    const int*   idx   = (const int*)d_in[2];
    const float* geo   = (const float*)d_in[3];
    const float* ang   = (const float*)d_in[4];
    const float* W0    = (const float*)d_in[5];
    const float* b0    = (const float*)d_in[6];
    const float* W1    = (const float*)d_in[7];
    const float* b1    = (const float*)d_in[8];
    const float* gamma = (const float*)d_in[9];
    const float* beta  = (const float*)d_in[10];
    const float* W2    = (const float*)d_in[11];
    const float* b2    = (const float*)d_in[12];
    const float* Wq    = (const float*)d_in[13];
    const float* bq    = (const float*)d_in[14];
    const float* Wk    = (const float*)d_in[15];
    const float* bk    = (const float*)d_in[16];

    float* ws   = (float*)d_ws;
    float* swp  = ws;              // 1
    float* W01g = ws + 256;        // 1280 (5 x 256, TL2E-prescaled)
    float* part = ws + 2048;       // 32 x 512 floats (zeroed by prep2)

    prep2_kernel<<<8, 256, 0, stream>>>(W0, b0, W1, b1, W2, b2, W01g, swp, part);
    stats_kernel<<<E_ / 128, 256, 0, stream>>>(coor, W01g, part);
    edge_kernel<<<N_ / 2, 256, 0, stream>>>(coor, idx, part, W01g, gamma, beta,
                                            W2, swp, Wq, bq, Wk, bk, geo, ang,
                                            (float*)d_out);
}